// Round 20
// baseline (184.668 us; speedup 1.0000x reference)
//
#include <hip/hip_runtime.h>
#include <hip/hip_bf16.h>

typedef __attribute__((ext_vector_type(8))) short s8v;   // 8 x bf16
typedef __attribute__((ext_vector_type(4))) float f32x4; // MFMA acc

__device__ __forceinline__ float sigf(float x) { return 1.0f / (1.0f + __expf(-x)); }
__device__ __forceinline__ float tanh_fast(float x) { return 1.0f - 2.0f / (1.0f + __expf(2.0f * x)); }
__device__ __forceinline__ ushort f2bf(float f) {
    union { __hip_bfloat16 b; ushort u; } v; v.b = __float2bfloat16(f); return v.u;
}

// ---------------- prepass (R16-proven) ----------------
__global__ __launch_bounds__(256) void prepass(
    const float* __restrict__ emb,
    const float* __restrict__ Wih, const float* __restrict__ Whh,
    const float* __restrict__ bih, const float* __restrict__ bhh,
    ushort* __restrict__ Bpack, float4* __restrict__ PX4, float4* __restrict__ Wcol4,
    ushort* __restrict__ HLEAF, float* __restrict__ CLEAF)
{
    const int bx = blockIdx.x;
    const int tid = threadIdx.x;
    if (bx < 64) {
        const int gid = bx * 256 + tid;     // (ty, j)
        const int ty = gid >> 7;
        const int j  = gid & 127;
        const float* e = emb + (size_t)ty * 128;
        float d[4];
        #pragma unroll
        for (int g = 0; g < 4; ++g) {
            const int row = g * 256 + j;
            const float* wr = Wih + (size_t)row * 128;
            float acc = bih[row] + bhh[row];
            #pragma unroll 8
            for (int k = 0; k < 128; k += 4) {
                float4 ev = *(const float4*)(e + k);
                float4 wv = *(const float4*)(wr + k);
                acc = fmaf(ev.x, wv.x, acc); acc = fmaf(ev.y, wv.y, acc);
                acc = fmaf(ev.z, wv.z, acc); acc = fmaf(ev.w, wv.w, acc);
            }
            d[g] = acc;
        }
        PX4[gid] = make_float4(d[0], d[1], d[2], d[3]);
        const float cn = sigf(d[0]) * tanh_fast(d[2]);
        CLEAF[gid] = cn;
        HLEAF[gid] = f2bf(sigf(d[3]) * tanh_fast(cn));
        if (ty == 0)
            Wcol4[j] = make_float4(Wih[(size_t)j * 128 + 127],
                                   Wih[(size_t)(256 + j) * 128 + 127],
                                   Wih[(size_t)(512 + j) * 128 + 127],
                                   Wih[(size_t)(768 + j) * 128 + 127]);
    } else {
        const int gid = (bx - 64) * 256 + tid;   // Bpack (Whh only, K=256)
        const int nl  = gid & 127;
        const int seg = (gid >> 7) & 3;
        const int rest = gid >> 9;
        const int kk = rest & 7;
        const int bn = rest >> 3;
        const int g  = (nl >> 4) & 3;
        const int j  = bn * 32 + ((nl >> 6) << 4) + (nl & 15);
        const int row = g * 256 + j;
        const int k = kk * 32 + seg * 8;
        const float* src = Whh + (size_t)row * 256 + k;
        float4 w0 = *(const float4*)(src);
        float4 w1 = *(const float4*)(src + 4);
        ushort o[8] = { f2bf(w0.x), f2bf(w0.y), f2bf(w0.z), f2bf(w0.w),
                        f2bf(w1.x), f2bf(w1.y), f2bf(w1.z), f2bf(w1.w) };
        *(s8v*)(Bpack + (size_t)gid * 8) = *(const s8v*)o;
    }
}

// ================= 4-wave (256-thread) M=16 helpers =================
// wave = bn (0..3); wn looped 0..1 -> j = bn*32 + wn*16 + lc; gates = f.
// A row (M=16): lane's lc; D row: seg*4 + r.

// children from LDS. OUT: 0 -> global h/c, 1 -> LDS.
template<int OUT>
__device__ __forceinline__ void g16_l4(
    int gbase, int nloc, int startL,
    const int* __restrict__ nt, const float* __restrict__ na,
    const ushort (*hIn)[136], const float (*cIn)[132],
    const ushort* __restrict__ Bpack, const float4* __restrict__ PX4,
    const float4* __restrict__ Wcol4, float e1, float e2,
    ushort* __restrict__ h_out, float* __restrict__ c_out,
    ushort (*hOL)[136], float (*cOL)[132])
{
    const int tid  = threadIdx.x;
    const int lane = tid & 63;
    const int bn   = tid >> 6;
    const int lc = lane & 15, seg = lane >> 4;
    const int koff = seg * 8;

    const int mcl = (lc < nloc) ? lc : nloc - 1;
    const ushort* pb0 = Bpack + (size_t)bn * 32768 + (size_t)seg * 1024 + (size_t)lc * 8;
    const ushort* pb1 = pb0 + 512;   // wn=1: +64 cols * 8

    f32x4 acc[2][4];
    #pragma unroll
    for (int wn = 0; wn < 2; ++wn)
        #pragma unroll
        for (int f = 0; f < 4; ++f) acc[wn][f] = (f32x4){0.f, 0.f, 0.f, 0.f};

    #pragma unroll
    for (int kk = 0; kk < 8; ++kk) {
        const int hi = kk >> 2, off = (kk & 3) * 32;
        s8v a = *(const s8v*)(&hIn[2 * mcl + hi][off + koff]);
        #pragma unroll
        for (int f = 0; f < 4; ++f) {
            s8v b0 = *(const s8v*)(pb0 + (size_t)kk * 4096 + f * 128);
            s8v b1 = *(const s8v*)(pb1 + (size_t)kk * 4096 + f * 128);
            acc[0][f] = __builtin_amdgcn_mfma_f32_16x16x32_bf16(a, b0, acc[0][f], 0, 0, 0);
            acc[1][f] = __builtin_amdgcn_mfma_f32_16x16x32_bf16(a, b1, acc[1][f], 0, 0, 0);
        }
    }

    #pragma unroll
    for (int wn = 0; wn < 2; ++wn) {
        const int j = bn * 32 + wn * 16 + lc;
        const float4 wc = Wcol4[j];
        #pragma unroll
        for (int r = 0; r < 4; ++r) {
            const int m = seg * 4 + r;
            if (m < nloc) {
                const int mPg = gbase + m;
                const int node = startL + mPg;
                const int ty = nt[node];
                const float corr = (ty == 1) ? (na[node] - e1)
                                 : ((ty == 2) ? (na[node] - e2) : 0.0f);
                const float4 px = PX4[(size_t)ty * 128 + j];
                const float gi = acc[wn][0][r] + px.x + corr * wc.x;
                const float gf = acc[wn][1][r] + px.y + corr * wc.y;
                const float gg = acc[wn][2][r] + px.z + corr * wc.z;
                const float go = acc[wn][3][r] + px.w + corr * wc.w;
                const float c0 = cIn[m][j];
                const float cn = sigf(gf) * c0 + sigf(gi) * tanh_fast(gg);
                const float hn = sigf(go) * tanh_fast(cn);
                if (OUT == 0) {
                    h_out[(size_t)mPg * 128 + j] = f2bf(hn);
                    if (!(mPg & 1)) c_out[(size_t)(mPg >> 1) * 128 + j] = cn;
                } else {
                    hOL[m][j] = f2bf(hn);
                    if (!(m & 1)) cOL[m >> 1][j] = cn;
                }
            }
        }
    }
}

// children from GLOBAL (level-indexed h_in; c_in compact at parent index). Writes LDS.
__device__ __forceinline__ void g16_g4(
    int rowbase, int nRows, int startL,
    const int* __restrict__ nt, const float* __restrict__ na,
    const ushort* __restrict__ h_in, const float* __restrict__ c_in,
    const ushort* __restrict__ Bpack, const float4* __restrict__ PX4,
    const float4* __restrict__ Wcol4, float e1, float e2,
    ushort (*hO)[136], float (*cO)[132])
{
    const int tid  = threadIdx.x;
    const int lane = tid & 63;
    const int bn   = tid >> 6;
    const int lc = lane & 15, seg = lane >> 4;
    const int koff = seg * 8;

    int dg = rowbase + lc;
    int dgc = dg < nRows ? dg : nRows - 1;
    const ushort* ph0 = h_in + (size_t)(2 * dgc) * 128 + koff;
    const ushort* ph1 = h_in + (size_t)(2 * dgc + 1) * 128 + koff;
    const ushort* pb0 = Bpack + (size_t)bn * 32768 + (size_t)seg * 1024 + (size_t)lc * 8;
    const ushort* pb1 = pb0 + 512;

    f32x4 acc[2][4];
    #pragma unroll
    for (int wn = 0; wn < 2; ++wn)
        #pragma unroll
        for (int f = 0; f < 4; ++f) acc[wn][f] = (f32x4){0.f, 0.f, 0.f, 0.f};

    #pragma unroll
    for (int kk = 0; kk < 8; ++kk) {
        const int hi = kk >> 2, off = (kk & 3) * 32;
        s8v a = *(const s8v*)((hi ? ph1 : ph0) + off);
        #pragma unroll
        for (int f = 0; f < 4; ++f) {
            s8v b0 = *(const s8v*)(pb0 + (size_t)kk * 4096 + f * 128);
            s8v b1 = *(const s8v*)(pb1 + (size_t)kk * 4096 + f * 128);
            acc[0][f] = __builtin_amdgcn_mfma_f32_16x16x32_bf16(a, b0, acc[0][f], 0, 0, 0);
            acc[1][f] = __builtin_amdgcn_mfma_f32_16x16x32_bf16(a, b1, acc[1][f], 0, 0, 0);
        }
    }

    #pragma unroll
    for (int wn = 0; wn < 2; ++wn) {
        const int j = bn * 32 + wn * 16 + lc;
        const float4 wc = Wcol4[j];
        #pragma unroll
        for (int r = 0; r < 4; ++r) {
            const int m = seg * 4 + r;
            const int dgr = rowbase + m;
            if (dgr < nRows) {
                const int node = startL + dgr;
                const int ty = nt[node];
                const float corr = (ty == 1) ? (na[node] - e1)
                                 : ((ty == 2) ? (na[node] - e2) : 0.0f);
                const float4 px = PX4[(size_t)ty * 128 + j];
                const float gi = acc[wn][0][r] + px.x + corr * wc.x;
                const float gf = acc[wn][1][r] + px.y + corr * wc.y;
                const float gg = acc[wn][2][r] + px.z + corr * wc.z;
                const float go = acc[wn][3][r] + px.w + corr * wc.w;
                const float c0 = c_in[(size_t)dgr * 128 + j];
                const float cn = sigf(gf) * c0 + sigf(gi) * tanh_fast(gg);
                const float hn = sigf(go) * tanh_fast(cn);
                hO[m][j] = f2bf(hn);
                if (!(m & 1)) cO[m >> 1][j] = cn;
            }
        }
    }
}

// ---------------- mega1: levels 15..11, 1024 blocks x 256 threads ----------------
__global__ __launch_bounds__(256) void mega1(
    const int* __restrict__ nt, const float* __restrict__ na,
    const float* __restrict__ emb,
    const ushort* __restrict__ Bpack, const float4* __restrict__ PX4,
    const float4* __restrict__ Wcol4,
    const ushort* __restrict__ HLEAF, const float* __restrict__ CLEAF,
    ushort* __restrict__ h_out, float* __restrict__ c_out)   // level-11
{
    __shared__ __align__(16) ushort hD[32][136];
    __shared__ float cD[16][132];
    __shared__ __align__(16) ushort hM[16][136];
    __shared__ float cM[8][132];

    const int tid = threadIdx.x;
    const int b = blockIdx.x;
    const float e1 = emb[255], e2 = emb[383];

    // stage 0: 32 leaves (level 15)
    {
        const int mloc = tid >> 3;      // 0..31
        const int p8   = tid & 7;
        const int node = 32767 + 32 * b + mloc;
        const int ty = nt[node];
        if (ty != 1 && ty != 2) {
            *(s8v*)(&hD[mloc][p8 * 16])     = *(const s8v*)(HLEAF + (size_t)ty * 128 + p8 * 16);
            *(s8v*)(&hD[mloc][p8 * 16 + 8]) = *(const s8v*)(HLEAF + (size_t)ty * 128 + p8 * 16 + 8);
            if (!(mloc & 1)) {
                const float* cr = CLEAF + (size_t)ty * 128 + p8 * 16;
                #pragma unroll
                for (int q = 0; q < 16; ++q) cD[mloc >> 1][p8 * 16 + q] = cr[q];
            }
        } else {
            const float corr = na[node] - ((ty == 1) ? e1 : e2);
            #pragma unroll
            for (int q = 0; q < 16; ++q) {
                const int jj = p8 * 16 + q;
                const float4 px = PX4[(size_t)ty * 128 + jj];
                const float4 wc = Wcol4[jj];
                const float gi = px.x + corr * wc.x;
                const float gg = px.z + corr * wc.z;
                const float go = px.w + corr * wc.w;
                const float cn = sigf(gi) * tanh_fast(gg);
                const float hn = sigf(go) * tanh_fast(cn);
                hD[mloc][jj] = f2bf(hn);
                if (!(mloc & 1)) cD[mloc >> 1][jj] = cn;
            }
        }
    }
    __syncthreads();
    g16_l4<1>(16 * b, 16, 16383, nt, na, hD, cD, Bpack, PX4, Wcol4, e1, e2,
              nullptr, nullptr, hM, cM);                        // L14
    __syncthreads();
    g16_l4<1>(8 * b, 8, 8191, nt, na, hM, cM, Bpack, PX4, Wcol4, e1, e2,
              nullptr, nullptr, hD, cD);                        // L13
    __syncthreads();
    g16_l4<1>(4 * b, 4, 4095, nt, na, hD, cD, Bpack, PX4, Wcol4, e1, e2,
              nullptr, nullptr, hM, cM);                        // L12
    __syncthreads();
    g16_l4<0>(2 * b, 2, 2047, nt, na, hM, cM, Bpack, PX4, Wcol4, e1, e2,
              h_out, c_out, nullptr, nullptr);                  // L11 -> global
}

// ---------------- mega2: levels 10..6, 64 blocks x 256 threads ----------------
__global__ __launch_bounds__(256) void mega2(
    const int* __restrict__ nt, const float* __restrict__ na,
    const float* __restrict__ emb,
    const ushort* __restrict__ Bpack, const float4* __restrict__ PX4,
    const float4* __restrict__ Wcol4,
    const ushort* __restrict__ h_in, const float* __restrict__ c_in,   // level-11
    ushort* __restrict__ h_out, float* __restrict__ c_out)             // level-6
{
    __shared__ __align__(16) ushort hD[16][136];
    __shared__ float cD[8][132];
    __shared__ __align__(16) ushort hM[16][136];
    __shared__ float cM[8][132];

    const int b = blockIdx.x;
    const float e1 = emb[255], e2 = emb[383];

    g16_g4(16 * b, 1024, 1023, nt, na, h_in, c_in,
           Bpack, PX4, Wcol4, e1, e2, hD, cD);                  // L10 (16 rows)
    __syncthreads();
    g16_l4<1>(8 * b, 8, 511, nt, na, hD, cD, Bpack, PX4, Wcol4, e1, e2,
              nullptr, nullptr, hM, cM);                        // L9
    __syncthreads();
    g16_l4<1>(4 * b, 4, 255, nt, na, hM, cM, Bpack, PX4, Wcol4, e1, e2,
              nullptr, nullptr, hD, cD);                        // L8
    __syncthreads();
    g16_l4<1>(2 * b, 2, 127, nt, na, hD, cD, Bpack, PX4, Wcol4, e1, e2,
              nullptr, nullptr, hM, cM);                        // L7
    __syncthreads();
    g16_l4<0>(b, 1, 63, nt, na, hM, cM, Bpack, PX4, Wcol4, e1, e2,
              h_out, c_out, nullptr, nullptr);                  // L6 -> global
}

// ================= 8-wave helpers for mega3 (R19-proven) =================
__device__ __forceinline__ void gemm64_g(
    int rowbase, int nRows, int startL,
    const int* __restrict__ nt, const float* __restrict__ na,
    const ushort* __restrict__ h_in, const float* __restrict__ c_in,
    const ushort* __restrict__ Bpack, const float4* __restrict__ PX4,
    const float4* __restrict__ Wcol4, float e1, float e2,
    ushort (*hO)[136], float (*cO)[132])
{
    const int tid  = threadIdx.x;
    const int lane = tid & 63;
    const int wave = tid >> 6;
    const int wm2 = wave >> 2;
    const int bn  = wave & 3;
    const int lc = lane & 15, seg = lane >> 4;
    const int koff = seg * 8;

    const ushort* ph[2][2];
    #pragma unroll
    for (int mi = 0; mi < 2; ++mi) {
        int mloc = wm2 * 32 + mi * 16 + lc;
        int dg = rowbase + mloc;
        int dgc = dg < nRows ? dg : nRows - 1;
        ph[mi][0] = h_in + (size_t)(2 * dgc) * 128 + koff;
        ph[mi][1] = h_in + (size_t)(2 * dgc + 1) * 128 + koff;
    }
    const ushort* pb = Bpack + (size_t)bn * 32768 + (size_t)seg * 1024
                             + (size_t)lc * 8;

    f32x4 acc[2][8];
    #pragma unroll
    for (int mi = 0; mi < 2; ++mi)
        #pragma unroll
        for (int f = 0; f < 8; ++f) acc[mi][f] = (f32x4){0.f, 0.f, 0.f, 0.f};

    #pragma unroll
    for (int kk = 0; kk < 8; ++kk) {
        const int hi = kk >> 2, off = (kk & 3) * 32;
        s8v a0 = *(const s8v*)(ph[0][hi] + off);
        s8v a1 = *(const s8v*)(ph[1][hi] + off);
        #pragma unroll
        for (int f = 0; f < 8; ++f) {
            s8v bb = *(const s8v*)(pb + (size_t)kk * 4096 + f * 128);
            acc[0][f] = __builtin_amdgcn_mfma_f32_16x16x32_bf16(a0, bb, acc[0][f], 0, 0, 0);
            acc[1][f] = __builtin_amdgcn_mfma_f32_16x16x32_bf16(a1, bb, acc[1][f], 0, 0, 0);
        }
    }
    #pragma unroll
    for (int bh = 0; bh < 2; ++bh) {
        const int j = bn * 32 + bh * 16 + lc;
        const float4 wc = Wcol4[j];
        #pragma unroll
        for (int mi = 0; mi < 2; ++mi) {
            #pragma unroll
            for (int r = 0; r < 4; ++r) {
                const int mloc = wm2 * 32 + mi * 16 + seg * 4 + r;
                const int dg = rowbase + mloc;
                if (dg < nRows) {
                    const int node = startL + dg;
                    const int ty = nt[node];
                    const float corr = (ty == 1) ? (na[node] - e1)
                                     : ((ty == 2) ? (na[node] - e2) : 0.0f);
                    const float4 px = PX4[(size_t)ty * 128 + j];
                    const float gi = acc[mi][bh * 4 + 0][r] + px.x + corr * wc.x;
                    const float gf = acc[mi][bh * 4 + 1][r] + px.y + corr * wc.y;
                    const float gg = acc[mi][bh * 4 + 2][r] + px.z + corr * wc.z;
                    const float go = acc[mi][bh * 4 + 3][r] + px.w + corr * wc.w;
                    const float c0 = c_in[(size_t)dg * 128 + j];
                    const float cn = sigf(gf) * c0 + sigf(gi) * tanh_fast(gg);
                    const float hn = sigf(go) * tanh_fast(cn);
                    hO[mloc][j] = f2bf(hn);
                    if (!(mloc & 1)) cO[mloc >> 1][j] = cn;
                }
            }
        }
    }
}

template<int OUT>   // 1=LDS, 2=root hs
__device__ __forceinline__ void gemm32_l(
    int gbase, int nloc, int startL,
    const int* __restrict__ nt, const float* __restrict__ na,
    const ushort (*hIn)[136], const float (*cIn)[132],
    const ushort* __restrict__ Bpack, const float4* __restrict__ PX4,
    const float4* __restrict__ Wcol4, float e1, float e2,
    ushort (*hOL)[136], float (*cOL)[132], float* hs)
{
    const int tid  = threadIdx.x;
    const int lane = tid & 63;
    const int wave = tid >> 6;
    const int bn = wave >> 1, wn = wave & 1;
    const int lc = lane & 15, seg = lane >> 4;
    const int koff = seg * 8;

    int mcl[2];
    #pragma unroll
    for (int mi = 0; mi < 2; ++mi) {
        int m = mi * 16 + lc;
        mcl[mi] = m < nloc ? m : nloc - 1;
    }
    const ushort* pb = Bpack + (size_t)bn * 32768 + (size_t)seg * 1024
                             + (size_t)(wn * 64 + lc) * 8;

    f32x4 acc[2][4];
    #pragma unroll
    for (int mi = 0; mi < 2; ++mi)
        #pragma unroll
        for (int f = 0; f < 4; ++f) acc[mi][f] = (f32x4){0.f, 0.f, 0.f, 0.f};

    #pragma unroll
    for (int kk = 0; kk < 8; ++kk) {
        const int hi = kk >> 2, off = (kk & 3) * 32;
        s8v a0 = *(const s8v*)(&hIn[2 * mcl[0] + hi][off + koff]);
        s8v a1 = *(const s8v*)(&hIn[2 * mcl[1] + hi][off + koff]);
        #pragma unroll
        for (int f = 0; f < 4; ++f) {
            s8v bb = *(const s8v*)(pb + (size_t)kk * 4096 + f * 128);
            acc[0][f] = __builtin_amdgcn_mfma_f32_16x16x32_bf16(a0, bb, acc[0][f], 0, 0, 0);
            acc[1][f] = __builtin_amdgcn_mfma_f32_16x16x32_bf16(a1, bb, acc[1][f], 0, 0, 0);
        }
    }

    const int j = bn * 32 + wn * 16 + lc;
    const float4 wc = Wcol4[j];
    #pragma unroll
    for (int mi = 0; mi < 2; ++mi) {
        #pragma unroll
        for (int r = 0; r < 4; ++r) {
            const int m = mi * 16 + seg * 4 + r;
            if (m < nloc) {
                const int node = startL + gbase + m;
                const int ty = nt[node];
                const float corr = (ty == 1) ? (na[node] - e1)
                                 : ((ty == 2) ? (na[node] - e2) : 0.0f);
                const float4 px = PX4[(size_t)ty * 128 + j];
                const float gi = acc[mi][0][r] + px.x + corr * wc.x;
                const float gf = acc[mi][1][r] + px.y + corr * wc.y;
                const float gg = acc[mi][2][r] + px.z + corr * wc.z;
                const float go = acc[mi][3][r] + px.w + corr * wc.w;
                const float c0 = cIn[m][j];
                const float cn = sigf(gf) * c0 + sigf(gi) * tanh_fast(gg);
                const float hn = sigf(go) * tanh_fast(cn);
                if (OUT == 1) {
                    hOL[m][j] = f2bf(hn);
                    if (!(m & 1)) cOL[m >> 1][j] = cn;
                } else {
                    hs[j] = hn;
                }
            }
        }
    }
}

// ---------------- mega3: levels 5..0 + MLP head, one block x 512 ----------------
__global__ __launch_bounds__(512) void mega3(
    const int* __restrict__ nt, const float* __restrict__ na,
    const float* __restrict__ emb,
    const ushort* __restrict__ Bpack, const float4* __restrict__ PX4,
    const float4* __restrict__ Wcol4,
    const ushort* __restrict__ h_in, const float* __restrict__ c_in,   // level-6
    const float* __restrict__ W1, const float* __restrict__ b1,
    const float* __restrict__ W2, const float* __restrict__ b2,
    const float* __restrict__ vmask, float* __restrict__ out)
{
    __shared__ __align__(16) ushort hD[64][136];
    __shared__ float cD[32][132];
    __shared__ __align__(16) ushort hM[32][136];
    __shared__ float cM[16][132];
    __shared__ float hs[128];
    __shared__ float as[128];

    const int tid = threadIdx.x;
    const float e1 = emb[255], e2 = emb[383];

    gemm64_g(0, 32, 31, nt, na, h_in, c_in,
             Bpack, PX4, Wcol4, e1, e2, hD, cD);               // L5 (32 rows)
    __syncthreads();
    gemm32_l<1>(0, 16, 15, nt, na, hD, cD, Bpack, PX4, Wcol4, e1, e2,
                hM, cM, nullptr);                              // L4
    __syncthreads();
    gemm32_l<1>(0, 8, 7, nt, na, hM, cM, Bpack, PX4, Wcol4, e1, e2,
                hD, cD, nullptr);                              // L3
    __syncthreads();
    gemm32_l<1>(0, 4, 3, nt, na, hD, cD, Bpack, PX4, Wcol4, e1, e2,
                hM, cM, nullptr);                              // L2
    __syncthreads();
    gemm32_l<1>(0, 2, 1, nt, na, hM, cM, Bpack, PX4, Wcol4, e1, e2,
                hD, cD, nullptr);                              // L1
    __syncthreads();
    gemm32_l<2>(0, 1, 0, nt, na, hD, cD, Bpack, PX4, Wcol4, e1, e2,
                nullptr, nullptr, hs);                         // L0 -> hs
    __syncthreads();
    if (tid < 128) {
        float a1h = b1[tid];
        #pragma unroll 4
        for (int k = 0; k < 128; ++k) a1h = fmaf(hs[k], W1[tid * 128 + k], a1h);
        as[tid] = fmaxf(a1h, 0.0f);
    }
    __syncthreads();
    if (tid < 32) {
        float l = b2[tid];
        #pragma unroll 4
        for (int k = 0; k < 128; ++k) l = fmaf(as[k], W2[tid * 128 + k], l);
        l = (l + logf(vmask[tid])) * (1.0f / 3.0f);
        float mx = l;
        #pragma unroll
        for (int o = 16; o >= 1; o >>= 1) mx = fmaxf(mx, __shfl_xor(mx, o, 32));
        const float e = __expf(l - mx);
        float s = e;
        #pragma unroll
        for (int o = 16; o >= 1; o >>= 1) s += __shfl_xor(s, o, 32);
        out[tid] = e / s;
    }
}

extern "C" void kernel_launch(void* const* d_in, const int* in_sizes, int n_in,
                              void* d_out, int out_size, void* d_ws, size_t ws_size,
                              hipStream_t stream)
{
    const int*   node_types = (const int*)  d_in[0];
    const float* node_args  = (const float*)d_in[1];
    const float* vmask      = (const float*)d_in[2];
    const float* emb        = (const float*)d_in[3];
    const float* Wih        = (const float*)d_in[4];
    const float* Whh        = (const float*)d_in[5];
    const float* bih        = (const float*)d_in[6];
    const float* bhh        = (const float*)d_in[7];
    const float* W1         = (const float*)d_in[8];
    const float* b1         = (const float*)d_in[9];
    const float* W2         = (const float*)d_in[10];
    const float* b2         = (const float*)d_in[11];

    char* w = (char*)d_ws;
    ushort* Bpack = (ushort*)(w);                 // 16384*8*2  = 262,144
    float4* PX4   = (float4*)(w + 262144);        // 16384*16   = 262,144
    float4* Wcol4 = (float4*)(w + 524288);        // 128*16     =   2,048
    ushort* HLEAF = (ushort*)(w + 526336);        // 16384*2    =  32,768
    float*  CLEAF = (float*) (w + 559104);        // 16384*4    =  65,536
    ushort* h11   = (ushort*)(w + 624640);        // 2048*128*2 = 524,288
    float*  c11   = (float*) (w + 1148928);       // 1024*128*4 = 524,288
    ushort* h6    = (ushort*)(w + 1673216);       // 64*128*2   =  16,384
    float*  c6    = (float*) (w + 1689600);       // 32*128*4   =  16,384

    float* out = (float*)d_out;

    prepass<<<128, 256, 0, stream>>>(emb, Wih, Whh, bih, bhh,
                                     Bpack, PX4, Wcol4, HLEAF, CLEAF);
    mega1<<<1024, 256, 0, stream>>>(node_types, node_args, emb,
                                    Bpack, PX4, Wcol4, HLEAF, CLEAF, h11, c11);
    mega2<<<64, 256, 0, stream>>>(node_types, node_args, emb,
                                  Bpack, PX4, Wcol4, h11, c11, h6, c6);
    mega3<<<1, 512, 0, stream>>>(node_types, node_args, emb,
                                 Bpack, PX4, Wcol4, h6, c6,
                                 W1, b1, W2, b2, vmask, out);
}

// Round 21
// 136.887 us; speedup vs baseline: 1.3491x; 1.3491x over previous
//
#include <hip/hip_runtime.h>
#include <hip/hip_bf16.h>

typedef __attribute__((ext_vector_type(8))) short s8v;   // 8 x bf16
typedef __attribute__((ext_vector_type(4))) float f32x4; // MFMA acc

__device__ __forceinline__ float sigf(float x) { return 1.0f / (1.0f + __expf(-x)); }
__device__ __forceinline__ float tanh_fast(float x) { return 1.0f - 2.0f / (1.0f + __expf(2.0f * x)); }
__device__ __forceinline__ ushort f2bf(float f) {
    union { __hip_bfloat16 b; ushort u; } v; v.b = __float2bfloat16(f); return v.u;
}

// ---------------- prepass (R16-proven) ----------------
__global__ __launch_bounds__(256) void prepass(
    const float* __restrict__ emb,
    const float* __restrict__ Wih, const float* __restrict__ Whh,
    const float* __restrict__ bih, const float* __restrict__ bhh,
    ushort* __restrict__ Bpack, float4* __restrict__ PX4, float4* __restrict__ Wcol4,
    ushort* __restrict__ HLEAF, float* __restrict__ CLEAF)
{
    const int bx = blockIdx.x;
    const int tid = threadIdx.x;
    if (bx < 64) {
        const int gid = bx * 256 + tid;     // (ty, j)
        const int ty = gid >> 7;
        const int j  = gid & 127;
        const float* e = emb + (size_t)ty * 128;
        float d[4];
        #pragma unroll
        for (int g = 0; g < 4; ++g) {
            const int row = g * 256 + j;
            const float* wr = Wih + (size_t)row * 128;
            float acc = bih[row] + bhh[row];
            #pragma unroll 8
            for (int k = 0; k < 128; k += 4) {
                float4 ev = *(const float4*)(e + k);
                float4 wv = *(const float4*)(wr + k);
                acc = fmaf(ev.x, wv.x, acc); acc = fmaf(ev.y, wv.y, acc);
                acc = fmaf(ev.z, wv.z, acc); acc = fmaf(ev.w, wv.w, acc);
            }
            d[g] = acc;
        }
        PX4[gid] = make_float4(d[0], d[1], d[2], d[3]);
        const float cn = sigf(d[0]) * tanh_fast(d[2]);
        CLEAF[gid] = cn;
        HLEAF[gid] = f2bf(sigf(d[3]) * tanh_fast(cn));
        if (ty == 0)
            Wcol4[j] = make_float4(Wih[(size_t)j * 128 + 127],
                                   Wih[(size_t)(256 + j) * 128 + 127],
                                   Wih[(size_t)(512 + j) * 128 + 127],
                                   Wih[(size_t)(768 + j) * 128 + 127]);
    } else {
        const int gid = (bx - 64) * 256 + tid;   // Bpack (Whh only, K=256)
        const int nl  = gid & 127;
        const int seg = (gid >> 7) & 3;
        const int rest = gid >> 9;
        const int kk = rest & 7;
        const int bn = rest >> 3;
        const int g  = (nl >> 4) & 3;
        const int j  = bn * 32 + ((nl >> 6) << 4) + (nl & 15);
        const int row = g * 256 + j;
        const int k = kk * 32 + seg * 8;
        const float* src = Whh + (size_t)row * 256 + k;
        float4 w0 = *(const float4*)(src);
        float4 w1 = *(const float4*)(src + 4);
        ushort o[8] = { f2bf(w0.x), f2bf(w0.y), f2bf(w0.z), f2bf(w0.w),
                        f2bf(w1.x), f2bf(w1.y), f2bf(w1.z), f2bf(w1.w) };
        *(s8v*)(Bpack + (size_t)gid * 8) = *(const s8v*)o;
    }
}

// ================= 8-wave helpers (R19-proven pressure) =================
// M=64, children h/c from GLOBAL -> LDS hO/cO.
__device__ __forceinline__ void gemm64_g(
    int rowbase, int nRows, int startL,
    const int* __restrict__ nt, const float* __restrict__ na,
    const ushort* __restrict__ h_in, const float* __restrict__ c_in,
    const ushort* __restrict__ Bpack, const float4* __restrict__ PX4,
    const float4* __restrict__ Wcol4, float e1, float e2,
    ushort (*hO)[136], float (*cO)[132])
{
    const int tid  = threadIdx.x;
    const int lane = tid & 63;
    const int wave = tid >> 6;
    const int wm2 = wave >> 2;
    const int bn  = wave & 3;
    const int lc = lane & 15, seg = lane >> 4;
    const int koff = seg * 8;

    const ushort* ph[2][2];
    #pragma unroll
    for (int mi = 0; mi < 2; ++mi) {
        int mloc = wm2 * 32 + mi * 16 + lc;
        int dg = rowbase + mloc;
        int dgc = dg < nRows ? dg : nRows - 1;
        ph[mi][0] = h_in + (size_t)(2 * dgc) * 128 + koff;
        ph[mi][1] = h_in + (size_t)(2 * dgc + 1) * 128 + koff;
    }
    const ushort* pb = Bpack + (size_t)bn * 32768 + (size_t)seg * 1024
                             + (size_t)lc * 8;

    f32x4 acc[2][8];
    #pragma unroll
    for (int mi = 0; mi < 2; ++mi)
        #pragma unroll
        for (int f = 0; f < 8; ++f) acc[mi][f] = (f32x4){0.f, 0.f, 0.f, 0.f};

    #pragma unroll
    for (int kk = 0; kk < 8; ++kk) {
        const int hi = kk >> 2, off = (kk & 3) * 32;
        s8v a0 = *(const s8v*)(ph[0][hi] + off);
        s8v a1 = *(const s8v*)(ph[1][hi] + off);
        #pragma unroll
        for (int f = 0; f < 8; ++f) {
            s8v bb = *(const s8v*)(pb + (size_t)kk * 4096 + f * 128);
            acc[0][f] = __builtin_amdgcn_mfma_f32_16x16x32_bf16(a0, bb, acc[0][f], 0, 0, 0);
            acc[1][f] = __builtin_amdgcn_mfma_f32_16x16x32_bf16(a1, bb, acc[1][f], 0, 0, 0);
        }
    }
    #pragma unroll
    for (int bh = 0; bh < 2; ++bh) {
        const int j = bn * 32 + bh * 16 + lc;
        const float4 wc = Wcol4[j];
        #pragma unroll
        for (int mi = 0; mi < 2; ++mi) {
            #pragma unroll
            for (int r = 0; r < 4; ++r) {
                const int mloc = wm2 * 32 + mi * 16 + seg * 4 + r;
                const int dg = rowbase + mloc;
                if (dg < nRows) {
                    const int node = startL + dg;
                    const int ty = nt[node];
                    const float corr = (ty == 1) ? (na[node] - e1)
                                     : ((ty == 2) ? (na[node] - e2) : 0.0f);
                    const float4 px = PX4[(size_t)ty * 128 + j];
                    const float gi = acc[mi][bh * 4 + 0][r] + px.x + corr * wc.x;
                    const float gf = acc[mi][bh * 4 + 1][r] + px.y + corr * wc.y;
                    const float gg = acc[mi][bh * 4 + 2][r] + px.z + corr * wc.z;
                    const float go = acc[mi][bh * 4 + 3][r] + px.w + corr * wc.w;
                    const float c0 = c_in[(size_t)dg * 128 + j];
                    const float cn = sigf(gf) * c0 + sigf(gi) * tanh_fast(gg);
                    const float hn = sigf(go) * tanh_fast(cn);
                    hO[mloc][j] = f2bf(hn);
                    if (!(mloc & 1)) cO[mloc >> 1][j] = cn;
                }
            }
        }
    }
}

// M=64, children h/c from LDS (hIn 128 rows, cIn 64 rows indexed by parent-local m) -> LDS hO/cO.
// Exactly 64 rows (no clamp). ONE call per stage (R17 lesson: no back-to-back unbarriered calls).
__device__ __forceinline__ void gemm64_l(
    int startL, int gbase,
    const int* __restrict__ nt, const float* __restrict__ na,
    const ushort (*hIn)[136], const float (*cIn)[132],
    const ushort* __restrict__ Bpack, const float4* __restrict__ PX4,
    const float4* __restrict__ Wcol4, float e1, float e2,
    ushort (*hO)[136], float (*cO)[132])
{
    const int tid  = threadIdx.x;
    const int lane = tid & 63;
    const int wave = tid >> 6;
    const int wm2 = wave >> 2;
    const int bn  = wave & 3;
    const int lc = lane & 15, seg = lane >> 4;
    const int koff = seg * 8;

    const int m0 = wm2 * 32 + lc;        // A rows for mi=0
    const int m1 = m0 + 16;              // mi=1
    const ushort* pb = Bpack + (size_t)bn * 32768 + (size_t)seg * 1024
                             + (size_t)lc * 8;

    f32x4 acc[2][8];
    #pragma unroll
    for (int mi = 0; mi < 2; ++mi)
        #pragma unroll
        for (int f = 0; f < 8; ++f) acc[mi][f] = (f32x4){0.f, 0.f, 0.f, 0.f};

    #pragma unroll
    for (int kk = 0; kk < 8; ++kk) {
        const int hi = kk >> 2, off = (kk & 3) * 32;
        s8v a0 = *(const s8v*)(&hIn[2 * m0 + hi][off + koff]);
        s8v a1 = *(const s8v*)(&hIn[2 * m1 + hi][off + koff]);
        #pragma unroll
        for (int f = 0; f < 8; ++f) {
            s8v bb = *(const s8v*)(pb + (size_t)kk * 4096 + f * 128);
            acc[0][f] = __builtin_amdgcn_mfma_f32_16x16x32_bf16(a0, bb, acc[0][f], 0, 0, 0);
            acc[1][f] = __builtin_amdgcn_mfma_f32_16x16x32_bf16(a1, bb, acc[1][f], 0, 0, 0);
        }
    }
    #pragma unroll
    for (int bh = 0; bh < 2; ++bh) {
        const int j = bn * 32 + bh * 16 + lc;
        const float4 wc = Wcol4[j];
        #pragma unroll
        for (int mi = 0; mi < 2; ++mi) {
            #pragma unroll
            for (int r = 0; r < 4; ++r) {
                const int mloc = wm2 * 32 + mi * 16 + seg * 4 + r;
                const int node = startL + gbase + mloc;
                const int ty = nt[node];
                const float corr = (ty == 1) ? (na[node] - e1)
                                 : ((ty == 2) ? (na[node] - e2) : 0.0f);
                const float4 px = PX4[(size_t)ty * 128 + j];
                const float gi = acc[mi][bh * 4 + 0][r] + px.x + corr * wc.x;
                const float gf = acc[mi][bh * 4 + 1][r] + px.y + corr * wc.y;
                const float gg = acc[mi][bh * 4 + 2][r] + px.z + corr * wc.z;
                const float go = acc[mi][bh * 4 + 3][r] + px.w + corr * wc.w;
                const float c0 = cIn[mloc][j];
                const float cn = sigf(gf) * c0 + sigf(gi) * tanh_fast(gg);
                const float hn = sigf(go) * tanh_fast(cn);
                hO[mloc][j] = f2bf(hn);
                if (!(mloc & 1)) cO[mloc >> 1][j] = cn;
            }
        }
    }
}

// M<=32, children from LDS. OUT: 0=global, 1=LDS, 2=root hs.
template<int OUT>
__device__ __forceinline__ void gemm32_l(
    int gbase, int nloc, int startL,
    const int* __restrict__ nt, const float* __restrict__ na,
    const ushort (*hIn)[136], const float (*cIn)[132],
    const ushort* __restrict__ Bpack, const float4* __restrict__ PX4,
    const float4* __restrict__ Wcol4, float e1, float e2,
    ushort* __restrict__ h_out, float* __restrict__ c_out,
    ushort (*hOL)[136], float (*cOL)[132], float* hs)
{
    const int tid  = threadIdx.x;
    const int lane = tid & 63;
    const int wave = tid >> 6;
    const int bn = wave >> 1, wn = wave & 1;
    const int lc = lane & 15, seg = lane >> 4;
    const int koff = seg * 8;

    int mcl[2];
    #pragma unroll
    for (int mi = 0; mi < 2; ++mi) {
        int m = mi * 16 + lc;
        mcl[mi] = m < nloc ? m : nloc - 1;
    }
    const ushort* pb = Bpack + (size_t)bn * 32768 + (size_t)seg * 1024
                             + (size_t)(wn * 64 + lc) * 8;

    f32x4 acc[2][4];
    #pragma unroll
    for (int mi = 0; mi < 2; ++mi)
        #pragma unroll
        for (int f = 0; f < 4; ++f) acc[mi][f] = (f32x4){0.f, 0.f, 0.f, 0.f};

    #pragma unroll
    for (int kk = 0; kk < 8; ++kk) {
        const int hi = kk >> 2, off = (kk & 3) * 32;
        s8v a0 = *(const s8v*)(&hIn[2 * mcl[0] + hi][off + koff]);
        s8v a1 = *(const s8v*)(&hIn[2 * mcl[1] + hi][off + koff]);
        #pragma unroll
        for (int f = 0; f < 4; ++f) {
            s8v bb = *(const s8v*)(pb + (size_t)kk * 4096 + f * 128);
            acc[0][f] = __builtin_amdgcn_mfma_f32_16x16x32_bf16(a0, bb, acc[0][f], 0, 0, 0);
            acc[1][f] = __builtin_amdgcn_mfma_f32_16x16x32_bf16(a1, bb, acc[1][f], 0, 0, 0);
        }
    }

    const int j = bn * 32 + wn * 16 + lc;
    const float4 wc = Wcol4[j];
    #pragma unroll
    for (int mi = 0; mi < 2; ++mi) {
        #pragma unroll
        for (int r = 0; r < 4; ++r) {
            const int m = mi * 16 + seg * 4 + r;
            if (m < nloc) {
                const int mPg = gbase + m;
                const int node = startL + mPg;
                const int ty = nt[node];
                const float corr = (ty == 1) ? (na[node] - e1)
                                 : ((ty == 2) ? (na[node] - e2) : 0.0f);
                const float4 px = PX4[(size_t)ty * 128 + j];
                const float gi = acc[mi][0][r] + px.x + corr * wc.x;
                const float gf = acc[mi][1][r] + px.y + corr * wc.y;
                const float gg = acc[mi][2][r] + px.z + corr * wc.z;
                const float go = acc[mi][3][r] + px.w + corr * wc.w;
                const float c0 = cIn[m][j];
                const float cn = sigf(gf) * c0 + sigf(gi) * tanh_fast(gg);
                const float hn = sigf(go) * tanh_fast(cn);
                if (OUT == 0) {
                    h_out[(size_t)mPg * 128 + j] = f2bf(hn);
                    if (!(mPg & 1)) c_out[(size_t)(mPg >> 1) * 128 + j] = cn;
                } else if (OUT == 1) {
                    hOL[m][j] = f2bf(hn);
                    if (!(m & 1)) cOL[m >> 1][j] = cn;
                } else {
                    hs[j] = hn;
                }
            }
        }
    }
}

// ---------------- mega1: levels 15..11, 256 blocks x 512 threads (128 leaves/block) ----------------
__global__ __launch_bounds__(512) void mega1(
    const int* __restrict__ nt, const float* __restrict__ na,
    const float* __restrict__ emb,
    const ushort* __restrict__ Bpack, const float4* __restrict__ PX4,
    const float4* __restrict__ Wcol4,
    const ushort* __restrict__ HLEAF, const float* __restrict__ CLEAF,
    ushort* __restrict__ h_out, float* __restrict__ c_out)   // level-11
{
    __shared__ __align__(16) ushort hD[128][136];   // 34.8 KB
    __shared__ float cD[64][132];                   // 33.8 KB
    __shared__ __align__(16) ushort hM[64][136];    // 17.4 KB
    __shared__ float cM[32][132];                   // 16.9 KB

    const int tid = threadIdx.x;
    const int b = blockIdx.x;
    const float e1 = emb[255], e2 = emb[383];

    // stage 0: 128 leaves (level 15) via HLEAF/CLEAF row copies
    {
        const int mloc = tid >> 2;   // 0..127
        const int p4   = tid & 3;    // 32-elem chunk
        const int node = 32767 + 128 * b + mloc;
        const int ty = nt[node];
        if (ty != 1 && ty != 2) {
            #pragma unroll
            for (int q = 0; q < 4; ++q)
                *(s8v*)(&hD[mloc][p4 * 32 + q * 8]) =
                    *(const s8v*)(HLEAF + (size_t)ty * 128 + p4 * 32 + q * 8);
            if (!(mloc & 1)) {
                const float* cr = CLEAF + (size_t)ty * 128 + p4 * 32;
                #pragma unroll
                for (int q = 0; q < 32; ++q) cD[mloc >> 1][p4 * 32 + q] = cr[q];
            }
        } else {
            const float corr = na[node] - ((ty == 1) ? e1 : e2);
            #pragma unroll
            for (int q = 0; q < 32; ++q) {
                const int jj = p4 * 32 + q;
                const float4 px = PX4[(size_t)ty * 128 + jj];
                const float4 wc = Wcol4[jj];
                const float gi = px.x + corr * wc.x;
                const float gg = px.z + corr * wc.z;
                const float go = px.w + corr * wc.w;
                const float cn = sigf(gi) * tanh_fast(gg);
                const float hn = sigf(go) * tanh_fast(cn);
                hD[mloc][jj] = f2bf(hn);
                if (!(mloc & 1)) cD[mloc >> 1][jj] = cn;
            }
        }
    }
    __syncthreads();
    gemm64_l(16383, 64 * b, nt, na, hD, cD, Bpack, PX4, Wcol4, e1, e2,
             hM, cM);                                          // L14 (M=64)
    __syncthreads();
    gemm32_l<1>(32 * b, 32, 8191, nt, na, hM, cM, Bpack, PX4, Wcol4, e1, e2,
                nullptr, nullptr, hD, cD, nullptr);            // L13 -> hD[0..31]
    __syncthreads();
    gemm32_l<1>(16 * b, 16, 4095, nt, na, hD, cD, Bpack, PX4, Wcol4, e1, e2,
                nullptr, nullptr, hM, cM, nullptr);            // L12 -> hM[0..15]
    __syncthreads();
    gemm32_l<0>(8 * b, 8, 2047, nt, na, hM, cM, Bpack, PX4, Wcol4, e1, e2,
                h_out, c_out, nullptr, nullptr, nullptr);      // L11 -> global
}

// ---------------- mega2: levels 10..6, 16 blocks x 512 threads (R19-proven) ----------------
__global__ __launch_bounds__(512) void mega2(
    const int* __restrict__ nt, const float* __restrict__ na,
    const float* __restrict__ emb,
    const ushort* __restrict__ Bpack, const float4* __restrict__ PX4,
    const float4* __restrict__ Wcol4,
    const ushort* __restrict__ h_in, const float* __restrict__ c_in,   // level-11
    ushort* __restrict__ h_out, float* __restrict__ c_out)             // level-6
{
    __shared__ __align__(16) ushort hD[64][136];
    __shared__ float cD[32][132];
    __shared__ __align__(16) ushort hM[32][136];
    __shared__ float cM[16][132];

    const int b = blockIdx.x;
    const float e1 = emb[255], e2 = emb[383];

    gemm64_g(64 * b, 1024, 1023, nt, na, h_in, c_in,
             Bpack, PX4, Wcol4, e1, e2, hD, cD);               // L10
    __syncthreads();
    gemm32_l<1>(32 * b, 32, 511, nt, na, hD, cD, Bpack, PX4, Wcol4, e1, e2,
                nullptr, nullptr, hM, cM, nullptr);            // L9
    __syncthreads();
    gemm32_l<1>(16 * b, 16, 255, nt, na, hM, cM, Bpack, PX4, Wcol4, e1, e2,
                nullptr, nullptr, hD, cD, nullptr);            // L8
    __syncthreads();
    gemm32_l<1>(8 * b, 8, 127, nt, na, hD, cD, Bpack, PX4, Wcol4, e1, e2,
                nullptr, nullptr, hM, cM, nullptr);            // L7
    __syncthreads();
    gemm32_l<0>(4 * b, 4, 63, nt, na, hM, cM, Bpack, PX4, Wcol4, e1, e2,
                h_out, c_out, nullptr, nullptr, nullptr);      // L6 -> global
}

// ---------------- mega3: levels 5..0 + MLP head, one block x 512 (R19-proven) ----------------
__global__ __launch_bounds__(512) void mega3(
    const int* __restrict__ nt, const float* __restrict__ na,
    const float* __restrict__ emb,
    const ushort* __restrict__ Bpack, const float4* __restrict__ PX4,
    const float4* __restrict__ Wcol4,
    const ushort* __restrict__ h_in, const float* __restrict__ c_in,   // level-6
    const float* __restrict__ W1, const float* __restrict__ b1,
    const float* __restrict__ W2, const float* __restrict__ b2,
    const float* __restrict__ vmask, float* __restrict__ out)
{
    __shared__ __align__(16) ushort hD[64][136];
    __shared__ float cD[32][132];
    __shared__ __align__(16) ushort hM[32][136];
    __shared__ float cM[16][132];
    __shared__ float hs[128];
    __shared__ float as[128];

    const int tid = threadIdx.x;
    const float e1 = emb[255], e2 = emb[383];

    gemm64_g(0, 32, 31, nt, na, h_in, c_in,
             Bpack, PX4, Wcol4, e1, e2, hD, cD);               // L5
    __syncthreads();
    gemm32_l<1>(0, 16, 15, nt, na, hD, cD, Bpack, PX4, Wcol4, e1, e2,
                nullptr, nullptr, hM, cM, nullptr);            // L4
    __syncthreads();
    gemm32_l<1>(0, 8, 7, nt, na, hM, cM, Bpack, PX4, Wcol4, e1, e2,
                nullptr, nullptr, hD, cD, nullptr);            // L3
    __syncthreads();
    gemm32_l<1>(0, 4, 3, nt, na, hD, cD, Bpack, PX4, Wcol4, e1, e2,
                nullptr, nullptr, hM, cM, nullptr);            // L2
    __syncthreads();
    gemm32_l<1>(0, 2, 1, nt, na, hM, cM, Bpack, PX4, Wcol4, e1, e2,
                nullptr, nullptr, hD, cD, nullptr);            // L1
    __syncthreads();
    gemm32_l<2>(0, 1, 0, nt, na, hD, cD, Bpack, PX4, Wcol4, e1, e2,
                nullptr, nullptr, nullptr, nullptr, hs);       // L0 -> hs
    __syncthreads();
    if (tid < 128) {
        float a1h = b1[tid];
        #pragma unroll 4
        for (int k = 0; k < 128; ++k) a1h = fmaf(hs[k], W1[tid * 128 + k], a1h);
        as[tid] = fmaxf(a1h, 0.0f);
    }
    __syncthreads();
    if (tid < 32) {
        float l = b2[tid];
        #pragma unroll 4
        for (int k = 0; k < 128; ++k) l = fmaf(as[k], W2[tid * 128 + k], l);
        l = (l + logf(vmask[tid])) * (1.0f / 3.0f);
        float mx = l;
        #pragma unroll
        for (int o = 16; o >= 1; o >>= 1) mx = fmaxf(mx, __shfl_xor(mx, o, 32));
        const float e = __expf(l - mx);
        float s = e;
        #pragma unroll
        for (int o = 16; o >= 1; o >>= 1) s += __shfl_xor(s, o, 32);
        out[tid] = e / s;
    }
}

extern "C" void kernel_launch(void* const* d_in, const int* in_sizes, int n_in,
                              void* d_out, int out_size, void* d_ws, size_t ws_size,
                              hipStream_t stream)
{
    const int*   node_types = (const int*)  d_in[0];
    const float* node_args  = (const float*)d_in[1];
    const float* vmask      = (const float*)d_in[2];
    const float* emb        = (const float*)d_in[3];
    const float* Wih        = (const float*)d_in[4];
    const float* Whh        = (const float*)d_in[5];
    const float* bih        = (const float*)d_in[6];
    const float* bhh        = (const float*)d_in[7];
    const float* W1         = (const float*)d_in[8];
    const float* b1         = (const float*)d_in[9];
    const float* W2         = (const float*)d_in[10];
    const float* b2         = (const float*)d_in[11];

    char* w = (char*)d_ws;
    ushort* Bpack = (ushort*)(w);                 // 16384*8*2  = 262,144
    float4* PX4   = (float4*)(w + 262144);        // 16384*16   = 262,144
    float4* Wcol4 = (float4*)(w + 524288);        // 128*16     =   2,048
    ushort* HLEAF = (ushort*)(w + 526336);        // 16384*2    =  32,768
    float*  CLEAF = (float*) (w + 559104);        // 16384*4    =  65,536
    ushort* h11   = (ushort*)(w + 624640);        // 2048*128*2 = 524,288
    float*  c11   = (float*) (w + 1148928);       // 1024*128*4 = 524,288
    ushort* h6    = (ushort*)(w + 1673216);       // 64*128*2   =  16,384
    float*  c6    = (float*) (w + 1689600);       // 32*128*4   =  16,384

    float* out = (float*)d_out;

    prepass<<<128, 256, 0, stream>>>(emb, Wih, Whh, bih, bhh,
                                     Bpack, PX4, Wcol4, HLEAF, CLEAF);
    mega1<<<256, 512, 0, stream>>>(node_types, node_args, emb,
                                   Bpack, PX4, Wcol4, HLEAF, CLEAF, h11, c11);
    mega2<<<16, 512, 0, stream>>>(node_types, node_args, emb,
                                  Bpack, PX4, Wcol4, h11, c11, h6, c6);
    mega3<<<1, 512, 0, stream>>>(node_types, node_args, emb,
                                 Bpack, PX4, Wcol4, h6, c6,
                                 W1, b1, W2, b2, vmask, out);
}

// Round 22
// 131.645 us; speedup vs baseline: 1.4028x; 1.0398x over previous
//
#include <hip/hip_runtime.h>
#include <hip/hip_bf16.h>

typedef __attribute__((ext_vector_type(8))) short s8v;   // 8 x bf16
typedef __attribute__((ext_vector_type(4))) float f32x4; // MFMA acc

__device__ __forceinline__ float sigf(float x) { return 1.0f / (1.0f + __expf(-x)); }
__device__ __forceinline__ float tanh_fast(float x) { return 1.0f - 2.0f / (1.0f + __expf(2.0f * x)); }
__device__ __forceinline__ ushort f2bf(float f) {
    union { __hip_bfloat16 b; ushort u; } v; v.b = __float2bfloat16(f); return v.u;
}

// ---------------- prepass ----------------
// PX4[ty*128+j] = {gi,gf,gg,go}; Wcol4[j]; HLEAF/CLEAF leaf rows; Bpack (Whh, K=256);
// NC[node] = {(float)ty, corr}  (corr = na - emb[ty][127] for ty in {1,2}, else 0).
__global__ __launch_bounds__(256) void prepass(
    const int* __restrict__ nt, const float* __restrict__ na,
    const float* __restrict__ emb,
    const float* __restrict__ Wih, const float* __restrict__ Whh,
    const float* __restrict__ bih, const float* __restrict__ bhh,
    ushort* __restrict__ Bpack, float4* __restrict__ PX4, float4* __restrict__ Wcol4,
    ushort* __restrict__ HLEAF, float* __restrict__ CLEAF, float2* __restrict__ NC)
{
    const int bx = blockIdx.x;
    const int tid = threadIdx.x;
    if (bx < 64) {
        const int gid = bx * 256 + tid;     // (ty, j)
        const int ty = gid >> 7;
        const int j  = gid & 127;
        const float* e = emb + (size_t)ty * 128;
        float d[4];
        #pragma unroll
        for (int g = 0; g < 4; ++g) {
            const int row = g * 256 + j;
            const float* wr = Wih + (size_t)row * 128;
            float acc = bih[row] + bhh[row];
            #pragma unroll 8
            for (int k = 0; k < 128; k += 4) {
                float4 ev = *(const float4*)(e + k);
                float4 wv = *(const float4*)(wr + k);
                acc = fmaf(ev.x, wv.x, acc); acc = fmaf(ev.y, wv.y, acc);
                acc = fmaf(ev.z, wv.z, acc); acc = fmaf(ev.w, wv.w, acc);
            }
            d[g] = acc;
        }
        PX4[gid] = make_float4(d[0], d[1], d[2], d[3]);
        const float cn = sigf(d[0]) * tanh_fast(d[2]);
        CLEAF[gid] = cn;
        HLEAF[gid] = f2bf(sigf(d[3]) * tanh_fast(cn));
        if (ty == 0)
            Wcol4[j] = make_float4(Wih[(size_t)j * 128 + 127],
                                   Wih[(size_t)(256 + j) * 128 + 127],
                                   Wih[(size_t)(512 + j) * 128 + 127],
                                   Wih[(size_t)(768 + j) * 128 + 127]);
    } else if (bx < 128) {
        const int gid = (bx - 64) * 256 + tid;   // Bpack (Whh only, K=256)
        const int nl  = gid & 127;
        const int seg = (gid >> 7) & 3;
        const int rest = gid >> 9;
        const int kk = rest & 7;
        const int bn = rest >> 3;
        const int g  = (nl >> 4) & 3;
        const int j  = bn * 32 + ((nl >> 6) << 4) + (nl & 15);
        const int row = g * 256 + j;
        const int k = kk * 32 + seg * 8;
        const float* src = Whh + (size_t)row * 256 + k;
        float4 w0 = *(const float4*)(src);
        float4 w1 = *(const float4*)(src + 4);
        ushort o[8] = { f2bf(w0.x), f2bf(w0.y), f2bf(w0.z), f2bf(w0.w),
                        f2bf(w1.x), f2bf(w1.y), f2bf(w1.z), f2bf(w1.w) };
        *(s8v*)(Bpack + (size_t)gid * 8) = *(const s8v*)o;
    } else {
        const int node = (bx - 128) * 256 + tid;
        if (node < 65535) {
            const int ty = nt[node];
            float corr = 0.0f;
            if (ty == 1) corr = na[node] - emb[255];
            else if (ty == 2) corr = na[node] - emb[383];
            NC[node] = make_float2((float)ty, corr);
        }
    }
}

// ================= 8-wave helpers (R21-proven pressure, NC epilogue) =================
// M=64, children h/c from GLOBAL -> LDS hO/cO.
__device__ __forceinline__ void gemm64_g(
    int rowbase, int nRows, int startL,
    const float2* __restrict__ NC,
    const ushort* __restrict__ h_in, const float* __restrict__ c_in,
    const ushort* __restrict__ Bpack, const float4* __restrict__ PX4,
    const float4* __restrict__ Wcol4,
    ushort (*hO)[136], float (*cO)[132])
{
    const int tid  = threadIdx.x;
    const int lane = tid & 63;
    const int wave = tid >> 6;
    const int wm2 = wave >> 2;
    const int bn  = wave & 3;
    const int lc = lane & 15, seg = lane >> 4;
    const int koff = seg * 8;

    const ushort* ph[2][2];
    #pragma unroll
    for (int mi = 0; mi < 2; ++mi) {
        int mloc = wm2 * 32 + mi * 16 + lc;
        int dg = rowbase + mloc;
        int dgc = dg < nRows ? dg : nRows - 1;
        ph[mi][0] = h_in + (size_t)(2 * dgc) * 128 + koff;
        ph[mi][1] = h_in + (size_t)(2 * dgc + 1) * 128 + koff;
    }
    const ushort* pb = Bpack + (size_t)bn * 32768 + (size_t)seg * 1024
                             + (size_t)lc * 8;

    f32x4 acc[2][8];
    #pragma unroll
    for (int mi = 0; mi < 2; ++mi)
        #pragma unroll
        for (int f = 0; f < 8; ++f) acc[mi][f] = (f32x4){0.f, 0.f, 0.f, 0.f};

    #pragma unroll
    for (int kk = 0; kk < 8; ++kk) {
        const int hi = kk >> 2, off = (kk & 3) * 32;
        s8v a0 = *(const s8v*)(ph[0][hi] + off);
        s8v a1 = *(const s8v*)(ph[1][hi] + off);
        #pragma unroll
        for (int f = 0; f < 8; ++f) {
            s8v bb = *(const s8v*)(pb + (size_t)kk * 4096 + f * 128);
            acc[0][f] = __builtin_amdgcn_mfma_f32_16x16x32_bf16(a0, bb, acc[0][f], 0, 0, 0);
            acc[1][f] = __builtin_amdgcn_mfma_f32_16x16x32_bf16(a1, bb, acc[1][f], 0, 0, 0);
        }
    }
    #pragma unroll
    for (int bh = 0; bh < 2; ++bh) {
        const int j = bn * 32 + bh * 16 + lc;
        const float4 wc = Wcol4[j];
        #pragma unroll
        for (int mi = 0; mi < 2; ++mi) {
            #pragma unroll
            for (int r = 0; r < 4; ++r) {
                const int mloc = wm2 * 32 + mi * 16 + seg * 4 + r;
                const int dg = rowbase + mloc;
                if (dg < nRows) {
                    const float2 nc = NC[startL + dg];
                    const int ty = (int)nc.x;
                    const float corr = nc.y;
                    const float4 px = PX4[(size_t)ty * 128 + j];
                    const float gi = acc[mi][bh * 4 + 0][r] + px.x + corr * wc.x;
                    const float gf = acc[mi][bh * 4 + 1][r] + px.y + corr * wc.y;
                    const float gg = acc[mi][bh * 4 + 2][r] + px.z + corr * wc.z;
                    const float go = acc[mi][bh * 4 + 3][r] + px.w + corr * wc.w;
                    const float c0 = c_in[(size_t)dg * 128 + j];
                    const float cn = sigf(gf) * c0 + sigf(gi) * tanh_fast(gg);
                    const float hn = sigf(go) * tanh_fast(cn);
                    hO[mloc][j] = f2bf(hn);
                    if (!(mloc & 1)) cO[mloc >> 1][j] = cn;
                }
            }
        }
    }
}

// M=64, children from LDS (hIn 128 rows) -> LDS hO/cO. Exactly 64 rows.
__device__ __forceinline__ void gemm64_l(
    int startL, int gbase,
    const float2* __restrict__ NC,
    const ushort (*hIn)[136], const float (*cIn)[132],
    const ushort* __restrict__ Bpack, const float4* __restrict__ PX4,
    const float4* __restrict__ Wcol4,
    ushort (*hO)[136], float (*cO)[132])
{
    const int tid  = threadIdx.x;
    const int lane = tid & 63;
    const int wave = tid >> 6;
    const int wm2 = wave >> 2;
    const int bn  = wave & 3;
    const int lc = lane & 15, seg = lane >> 4;
    const int koff = seg * 8;

    const int m0 = wm2 * 32 + lc;
    const int m1 = m0 + 16;
    const ushort* pb = Bpack + (size_t)bn * 32768 + (size_t)seg * 1024
                             + (size_t)lc * 8;

    f32x4 acc[2][8];
    #pragma unroll
    for (int mi = 0; mi < 2; ++mi)
        #pragma unroll
        for (int f = 0; f < 8; ++f) acc[mi][f] = (f32x4){0.f, 0.f, 0.f, 0.f};

    #pragma unroll
    for (int kk = 0; kk < 8; ++kk) {
        const int hi = kk >> 2, off = (kk & 3) * 32;
        s8v a0 = *(const s8v*)(&hIn[2 * m0 + hi][off + koff]);
        s8v a1 = *(const s8v*)(&hIn[2 * m1 + hi][off + koff]);
        #pragma unroll
        for (int f = 0; f < 8; ++f) {
            s8v bb = *(const s8v*)(pb + (size_t)kk * 4096 + f * 128);
            acc[0][f] = __builtin_amdgcn_mfma_f32_16x16x32_bf16(a0, bb, acc[0][f], 0, 0, 0);
            acc[1][f] = __builtin_amdgcn_mfma_f32_16x16x32_bf16(a1, bb, acc[1][f], 0, 0, 0);
        }
    }
    #pragma unroll
    for (int bh = 0; bh < 2; ++bh) {
        const int j = bn * 32 + bh * 16 + lc;
        const float4 wc = Wcol4[j];
        #pragma unroll
        for (int mi = 0; mi < 2; ++mi) {
            #pragma unroll
            for (int r = 0; r < 4; ++r) {
                const int mloc = wm2 * 32 + mi * 16 + seg * 4 + r;
                const float2 nc = NC[startL + gbase + mloc];
                const int ty = (int)nc.x;
                const float corr = nc.y;
                const float4 px = PX4[(size_t)ty * 128 + j];
                const float gi = acc[mi][bh * 4 + 0][r] + px.x + corr * wc.x;
                const float gf = acc[mi][bh * 4 + 1][r] + px.y + corr * wc.y;
                const float gg = acc[mi][bh * 4 + 2][r] + px.z + corr * wc.z;
                const float go = acc[mi][bh * 4 + 3][r] + px.w + corr * wc.w;
                const float c0 = cIn[mloc][j];
                const float cn = sigf(gf) * c0 + sigf(gi) * tanh_fast(gg);
                const float hn = sigf(go) * tanh_fast(cn);
                hO[mloc][j] = f2bf(hn);
                if (!(mloc & 1)) cO[mloc >> 1][j] = cn;
            }
        }
    }
}

// M<=32, children from LDS. OUT: 0=global, 1=LDS, 2=root hs.
template<int OUT>
__device__ __forceinline__ void gemm32_l(
    int gbase, int nloc, int startL,
    const float2* __restrict__ NC,
    const ushort (*hIn)[136], const float (*cIn)[132],
    const ushort* __restrict__ Bpack, const float4* __restrict__ PX4,
    const float4* __restrict__ Wcol4,
    ushort* __restrict__ h_out, float* __restrict__ c_out,
    ushort (*hOL)[136], float (*cOL)[132], float* hs)
{
    const int tid  = threadIdx.x;
    const int lane = tid & 63;
    const int wave = tid >> 6;
    const int bn = wave >> 1, wn = wave & 1;
    const int lc = lane & 15, seg = lane >> 4;
    const int koff = seg * 8;

    int mcl[2];
    #pragma unroll
    for (int mi = 0; mi < 2; ++mi) {
        int m = mi * 16 + lc;
        mcl[mi] = m < nloc ? m : nloc - 1;
    }
    const ushort* pb = Bpack + (size_t)bn * 32768 + (size_t)seg * 1024
                             + (size_t)(wn * 64 + lc) * 8;

    f32x4 acc[2][4];
    #pragma unroll
    for (int mi = 0; mi < 2; ++mi)
        #pragma unroll
        for (int f = 0; f < 4; ++f) acc[mi][f] = (f32x4){0.f, 0.f, 0.f, 0.f};

    #pragma unroll
    for (int kk = 0; kk < 8; ++kk) {
        const int hi = kk >> 2, off = (kk & 3) * 32;
        s8v a0 = *(const s8v*)(&hIn[2 * mcl[0] + hi][off + koff]);
        s8v a1 = *(const s8v*)(&hIn[2 * mcl[1] + hi][off + koff]);
        #pragma unroll
        for (int f = 0; f < 4; ++f) {
            s8v bb = *(const s8v*)(pb + (size_t)kk * 4096 + f * 128);
            acc[0][f] = __builtin_amdgcn_mfma_f32_16x16x32_bf16(a0, bb, acc[0][f], 0, 0, 0);
            acc[1][f] = __builtin_amdgcn_mfma_f32_16x16x32_bf16(a1, bb, acc[1][f], 0, 0, 0);
        }
    }

    const int j = bn * 32 + wn * 16 + lc;
    const float4 wc = Wcol4[j];
    #pragma unroll
    for (int mi = 0; mi < 2; ++mi) {
        #pragma unroll
        for (int r = 0; r < 4; ++r) {
            const int m = mi * 16 + seg * 4 + r;
            if (m < nloc) {
                const int mPg = gbase + m;
                const float2 nc = NC[startL + mPg];
                const int ty = (int)nc.x;
                const float corr = nc.y;
                const float4 px = PX4[(size_t)ty * 128 + j];
                const float gi = acc[mi][0][r] + px.x + corr * wc.x;
                const float gf = acc[mi][1][r] + px.y + corr * wc.y;
                const float gg = acc[mi][2][r] + px.z + corr * wc.z;
                const float go = acc[mi][3][r] + px.w + corr * wc.w;
                const float c0 = cIn[m][j];
                const float cn = sigf(gf) * c0 + sigf(gi) * tanh_fast(gg);
                const float hn = sigf(go) * tanh_fast(cn);
                if (OUT == 0) {
                    h_out[(size_t)mPg * 128 + j] = f2bf(hn);
                    if (!(mPg & 1)) c_out[(size_t)(mPg >> 1) * 128 + j] = cn;
                } else if (OUT == 1) {
                    hOL[m][j] = f2bf(hn);
                    if (!(m & 1)) cOL[m >> 1][j] = cn;
                } else {
                    hs[j] = hn;
                }
            }
        }
    }
}

// ---------------- mega1: levels 15..12, 256 blocks x 512 (128 leaves/block) ----------------
__global__ __launch_bounds__(512) void mega1(
    const float2* __restrict__ NC,
    const ushort* __restrict__ Bpack, const float4* __restrict__ PX4,
    const float4* __restrict__ Wcol4,
    const ushort* __restrict__ HLEAF, const float* __restrict__ CLEAF,
    ushort* __restrict__ h_out, float* __restrict__ c_out)   // level-12
{
    __shared__ __align__(16) ushort hD[128][136];
    __shared__ float cD[64][132];
    __shared__ __align__(16) ushort hM[64][136];
    __shared__ float cM[32][132];

    const int tid = threadIdx.x;
    const int b = blockIdx.x;

    // stage 0: 128 leaves via HLEAF/CLEAF row copies
    {
        const int mloc = tid >> 2;   // 0..127
        const int p4   = tid & 3;    // 32-elem chunk
        const int node = 32767 + 128 * b + mloc;
        const float2 nc = NC[node];
        const int ty = (int)nc.x;
        if (ty != 1 && ty != 2) {
            #pragma unroll
            for (int q = 0; q < 4; ++q)
                *(s8v*)(&hD[mloc][p4 * 32 + q * 8]) =
                    *(const s8v*)(HLEAF + (size_t)ty * 128 + p4 * 32 + q * 8);
            if (!(mloc & 1)) {
                const float4* cr = (const float4*)(CLEAF + (size_t)ty * 128 + p4 * 32);
                float4* cw = (float4*)(&cD[mloc >> 1][p4 * 32]);
                #pragma unroll
                for (int q = 0; q < 8; ++q) cw[q] = cr[q];
            }
        } else {
            const float corr = nc.y;
            #pragma unroll
            for (int q = 0; q < 32; ++q) {
                const int jj = p4 * 32 + q;
                const float4 px = PX4[(size_t)ty * 128 + jj];
                const float4 wc = Wcol4[jj];
                const float gi = px.x + corr * wc.x;
                const float gg = px.z + corr * wc.z;
                const float go = px.w + corr * wc.w;
                const float cn = sigf(gi) * tanh_fast(gg);
                const float hn = sigf(go) * tanh_fast(cn);
                hD[mloc][jj] = f2bf(hn);
                if (!(mloc & 1)) cD[mloc >> 1][jj] = cn;
            }
        }
    }
    __syncthreads();
    gemm64_l(16383, 64 * b, NC, hD, cD, Bpack, PX4, Wcol4, hM, cM);   // L14
    __syncthreads();
    gemm32_l<1>(32 * b, 32, 8191, NC, hM, cM, Bpack, PX4, Wcol4,
                nullptr, nullptr, hD, cD, nullptr);                    // L13
    __syncthreads();
    gemm32_l<0>(16 * b, 16, 4095, NC, hD, cD, Bpack, PX4, Wcol4,
                h_out, c_out, nullptr, nullptr, nullptr);              // L12 -> global
}

// ---------------- mega2: levels 11..6, 32 blocks x 512 ----------------
__global__ __launch_bounds__(512) void mega2(
    const float2* __restrict__ NC,
    const ushort* __restrict__ Bpack, const float4* __restrict__ PX4,
    const float4* __restrict__ Wcol4,
    const ushort* __restrict__ h_in, const float* __restrict__ c_in,   // level-12
    ushort* __restrict__ h_out, float* __restrict__ c_out)             // level-6
{
    __shared__ __align__(16) ushort hD[64][136];
    __shared__ float cD[32][132];
    __shared__ __align__(16) ushort hM[32][136];
    __shared__ float cM[16][132];

    const int b = blockIdx.x;

    gemm64_g(64 * b, 2048, 2047, NC, h_in, c_in,
             Bpack, PX4, Wcol4, hD, cD);                               // L11
    __syncthreads();
    gemm32_l<1>(32 * b, 32, 1023, NC, hD, cD, Bpack, PX4, Wcol4,
                nullptr, nullptr, hM, cM, nullptr);                    // L10
    __syncthreads();
    gemm32_l<1>(16 * b, 16, 511, NC, hM, cM, Bpack, PX4, Wcol4,
                nullptr, nullptr, hD, cD, nullptr);                    // L9
    __syncthreads();
    gemm32_l<1>(8 * b, 8, 255, NC, hD, cD, Bpack, PX4, Wcol4,
                nullptr, nullptr, hM, cM, nullptr);                    // L8
    __syncthreads();
    gemm32_l<1>(4 * b, 4, 127, NC, hM, cM, Bpack, PX4, Wcol4,
                nullptr, nullptr, hD, cD, nullptr);                    // L7
    __syncthreads();
    gemm32_l<0>(2 * b, 2, 63, NC, hD, cD, Bpack, PX4, Wcol4,
                h_out, c_out, nullptr, nullptr, nullptr);              // L6 -> global
}

// ---------------- mega3: levels 5..0 + MLP head, one block x 512 ----------------
__global__ __launch_bounds__(512) void mega3(
    const float2* __restrict__ NC,
    const ushort* __restrict__ Bpack, const float4* __restrict__ PX4,
    const float4* __restrict__ Wcol4,
    const ushort* __restrict__ h_in, const float* __restrict__ c_in,   // level-6
    const float* __restrict__ W1, const float* __restrict__ b1,
    const float* __restrict__ W2, const float* __restrict__ b2,
    const float* __restrict__ vmask, float* __restrict__ out)
{
    __shared__ __align__(16) ushort hD[64][136];
    __shared__ float cD[32][132];
    __shared__ __align__(16) ushort hM[32][136];
    __shared__ float cM[16][132];
    __shared__ float hs[128];
    __shared__ float as[128];

    const int tid = threadIdx.x;

    gemm64_g(0, 32, 31, NC, h_in, c_in, Bpack, PX4, Wcol4, hD, cD);    // L5
    __syncthreads();
    gemm32_l<1>(0, 16, 15, NC, hD, cD, Bpack, PX4, Wcol4,
                nullptr, nullptr, hM, cM, nullptr);                    // L4
    __syncthreads();
    gemm32_l<1>(0, 8, 7, NC, hM, cM, Bpack, PX4, Wcol4,
                nullptr, nullptr, hD, cD, nullptr);                    // L3
    __syncthreads();
    gemm32_l<1>(0, 4, 3, NC, hD, cD, Bpack, PX4, Wcol4,
                nullptr, nullptr, hM, cM, nullptr);                    // L2
    __syncthreads();
    gemm32_l<1>(0, 2, 1, NC, hM, cM, Bpack, PX4, Wcol4,
                nullptr, nullptr, hD, cD, nullptr);                    // L1
    __syncthreads();
    gemm32_l<2>(0, 1, 0, NC, hD, cD, Bpack, PX4, Wcol4,
                nullptr, nullptr, nullptr, nullptr, hs);               // L0 -> hs
    __syncthreads();
    if (tid < 128) {
        float a1h = b1[tid];
        #pragma unroll 4
        for (int k = 0; k < 128; ++k) a1h = fmaf(hs[k], W1[tid * 128 + k], a1h);
        as[tid] = fmaxf(a1h, 0.0f);
    }
    __syncthreads();
    if (tid < 32) {
        float l = b2[tid];
        #pragma unroll 4
        for (int k = 0; k < 128; ++k) l = fmaf(as[k], W2[tid * 128 + k], l);
        l = (l + logf(vmask[tid])) * (1.0f / 3.0f);
        float mx = l;
        #pragma unroll
        for (int o = 16; o >= 1; o >>= 1) mx = fmaxf(mx, __shfl_xor(mx, o, 32));
        const float e = __expf(l - mx);
        float s = e;
        #pragma unroll
        for (int o = 16; o >= 1; o >>= 1) s += __shfl_xor(s, o, 32);
        out[tid] = e / s;
    }
}

extern "C" void kernel_launch(void* const* d_in, const int* in_sizes, int n_in,
                              void* d_out, int out_size, void* d_ws, size_t ws_size,
                              hipStream_t stream)
{
    const int*   node_types = (const int*)  d_in[0];
    const float* node_args  = (const float*)d_in[1];
    const float* vmask      = (const float*)d_in[2];
    const float* emb        = (const float*)d_in[3];
    const float* Wih        = (const float*)d_in[4];
    const float* Whh        = (const float*)d_in[5];
    const float* bih        = (const float*)d_in[6];
    const float* bhh        = (const float*)d_in[7];
    const float* W1         = (const float*)d_in[8];
    const float* b1         = (const float*)d_in[9];
    const float* W2         = (const float*)d_in[10];
    const float* b2         = (const float*)d_in[11];

    char* w = (char*)d_ws;
    ushort* Bpack = (ushort*)(w);                 // 262,144
    float4* PX4   = (float4*)(w + 262144);        // 262,144
    float4* Wcol4 = (float4*)(w + 524288);        // 2,048
    ushort* HLEAF = (ushort*)(w + 526336);        // 32,768
    float*  CLEAF = (float*) (w + 559104);        // 65,536
    float2* NC    = (float2*)(w + 624640);        // 65536*8 = 524,288
    ushort* h12   = (ushort*)(w + 1148928);       // 4096*128*2 = 1,048,576
    float*  c12   = (float*) (w + 2197504);       // 2048*128*4 = 1,048,576
    ushort* h6    = (ushort*)(w + 3246080);       // 64*128*2 = 16,384
    float*  c6    = (float*) (w + 3262464);       // 32*128*4 = 16,384

    float* out = (float*)d_out;

    prepass<<<384, 256, 0, stream>>>(node_types, node_args, emb,
                                     Wih, Whh, bih, bhh,
                                     Bpack, PX4, Wcol4, HLEAF, CLEAF, NC);
    mega1<<<256, 512, 0, stream>>>(NC, Bpack, PX4, Wcol4, HLEAF, CLEAF, h12, c12);
    mega2<<<32, 512, 0, stream>>>(NC, Bpack, PX4, Wcol4, h12, c12, h6, c6);
    mega3<<<1, 512, 0, stream>>>(NC, Bpack, PX4, Wcol4, h6, c6,
                                 W1, b1, W2, b2, vmask, out);
}